// Round 5
// baseline (750.347 us; speedup 1.0000x reference)
//
#include <hip/hip_runtime.h>

#define NUM_E 320000
#define NUM_N 10000
#define PADC 32   // ints of stride per counter: one counter per 128B L2 line

typedef __attribute__((ext_vector_type(8))) short bf16x8;
typedef __attribute__((ext_vector_type(4))) float f32x4;

// RNE fp32 -> bf16
__device__ __forceinline__ short f2bf(float f) {
  unsigned u = __builtin_bit_cast(unsigned, f);
  u += 0x7FFFu + ((u >> 16) & 1u);
  return (short)(u >> 16);
}

// RNE-pack two fp32 -> (bf16(y)<<16)|bf16(x) via v_perm_b32 (same rounding math)
__device__ __forceinline__ unsigned pack2bf(float x, float y) {
  unsigned ux = __builtin_bit_cast(unsigned, x);
  unsigned uy = __builtin_bit_cast(unsigned, y);
  ux += 0x7FFFu + ((ux >> 16) & 1u);
  uy += 0x7FFFu + ((uy >> 16) & 1u);
  return __builtin_amdgcn_perm(uy, ux, 0x07060302u);
}

// ---- k0: zero out (10.24MB) + zero padded counters + cursor + repack weights ----
__global__ __launch_bounds__(256) void zero_repack_k(
    const float* __restrict__ W1, const float* __restrict__ W2,
    short* __restrict__ Wp, int* __restrict__ cntA, int* __restrict__ cursor,
    float* __restrict__ out) {
  const int gtid = blockIdx.x * 256 + threadIdx.x;
  const int gsz = gridDim.x * 256;
  if (gtid == 0) *cursor = 0;
  for (int i = gtid; i < 640000; i += gsz)
    reinterpret_cast<float4*>(out)[i] = make_float4(0.f, 0.f, 0.f, 0.f);
  for (int i = gtid; i < NUM_N * PADC / 4; i += gsz)
    reinterpret_cast<int4*>(cntA)[i] = make_int4(0, 0, 0, 0);
  if (gtid < 16384) {
    // W[k][n] fp32 -> MFMA B-fragment bf16
    const float* W = (gtid & 8192) ? W2 : W1;
    int r = gtid & 8191;
    short* dst = Wp + (gtid >> 13) * 65536 + r * 8;
    int j = r >> 9;
    int s = (r >> 6) & 7;
    int lane = r & 63;
    int n = j * 16 + (lane & 15);
    int k0 = s * 32 + (lane >> 4) * 8;
    short tmp[8];
#pragma unroll
    for (int e = 0; e < 8; ++e) tmp[e] = f2bf(W[(k0 + e) * 256 + n]);
#pragma unroll
    for (int e = 0; e < 8; ++e) dst[e] = tmp[e];
  }
}

// ---- k1: histogram into line-padded counters ----
__global__ __launch_bounds__(256) void hist_k(const int* __restrict__ idx,
                                              int* __restrict__ cntA) {
  int e = blockIdx.x * 256 + threadIdx.x;
  if (e < NUM_E) atomicAdd(&cntA[idx[e] * PADC], 1);
}

// ---- k2: parallel segment-offset allocation (order-free, no global scan) ----
__global__ __launch_bounds__(256) void alloc_k(const int* __restrict__ cntA,
                                               int* __restrict__ fillP,
                                               float* __restrict__ inv,
                                               int* __restrict__ cursor) {
  int n = blockIdx.x * 256 + threadIdx.x;
  int lane = threadIdx.x & 63;
  int c = (n < NUM_N) ? cntA[n * PADC] : 0;
  int pre = c;
#pragma unroll
  for (int off = 1; off < 64; off <<= 1) {
    int v = __shfl_up(pre, off, 64);
    if (lane >= off) pre += v;
  }
  int tot = __shfl(pre, 63, 64);
  int base = 0;
  if (lane == 63) base = atomicAdd(cursor, tot);
  base = __shfl(base, 63, 64);
  if (n < NUM_N) {
    fillP[n * PADC] = base + pre - c;
    inv[n] = (c > 0) ? 1.0f / (float)c : 0.0f;
  }
}

// ---- k3: counting-sort scatter via line-padded fill cursors ----
__global__ __launch_bounds__(256) void scatter_k(const int* __restrict__ idx,
                                                 int* __restrict__ fillP,
                                                 int* __restrict__ sorted) {
  int e = blockIdx.x * 256 + threadIdx.x;
  if (e < NUM_E) {
    int ix = idx[e];
    int pos = atomicAdd(&fillP[ix * PADC], 1);
    sorted[pos] = e;
  }
}

// ---- fused MLP: 4 pipelined 64-edge tiles per block, double-buffered LDS ----
// Gather loads for tile t+1 issue BEFORE tile t's MFMA phases; consumed (vmcnt)
// only at the end of tile t -> HBM latency hides under ~3000 cyc of compute.
__global__ __launch_bounds__(256, 2) void fused_mlp_gather(
    const float* __restrict__ X, const int* __restrict__ idx,
    const int* __restrict__ sorted,
    const short* __restrict__ Wp1, const short* __restrict__ Wp2,
    const float* __restrict__ b1, const float* __restrict__ b2,
    const float* __restrict__ inv, float* __restrict__ out) {
  __shared__ __align__(16) short Xl[2][64][264];  // 67.6 KB: X then Y1, per tile
  __shared__ int segLo[2][64];
  __shared__ int segN[2][64];
  __shared__ int nsegS[2];

  const int tid = threadIdx.x;
  const int wave = tid >> 6;
  const int lane = tid & 63;
  const int q = lane >> 4;
  const int m = lane & 15;
  const int row0 = blockIdx.x * 256;   // 4 tiles x 64 edges per block

  float bias1v[4], bias2v[4];
#pragma unroll
  for (int nj = 0; nj < 4; ++nj) {
    bias1v[nj] = b1[wave * 64 + nj * 16 + m];
    bias2v[nj] = b2[wave * 64 + nj * 16 + m];
  }

  float4 vbuf[16];   // in-flight gather for the NEXT tile (64 VGPR, held)

  // ---- prologue: tile 0 meta + gather + pack ----
  {
    int ew = sorted[row0 + lane];
    if (wave == 0) {
      int ix = idx[ew];
      int prev = __shfl_up(ix, 1, 64);
      bool flag = (lane == 0) || (ix != prev);
      unsigned long long mask = __ballot(flag);
      if (lane == 0) nsegS[0] = (int)__popcll(mask);
      if (flag) {
        int sidx = (int)__popcll(mask & ((1ull << lane) - 1ull));
        segLo[0][sidx] = lane;
        segN[0][sidx] = ix;
      }
    }
#pragma unroll
    for (int k = 0; k < 16; ++k) {
      int e = __shfl(ew, k * 4 + wave, 64);
      vbuf[k] = reinterpret_cast<const float4*>(X + (size_t)e * 256)[lane];
    }
#pragma unroll
    for (int k = 0; k < 16; ++k) {
      uint2 pk;
      pk.x = pack2bf(vbuf[k].x, vbuf[k].y);
      pk.y = pack2bf(vbuf[k].z, vbuf[k].w);
      *reinterpret_cast<uint2*>(&Xl[0][k * 4 + wave][lane * 4]) = pk;
    }
  }

  for (int t = 0; t < 4; ++t) {
    const int p = t & 1;

    // -- R1: issue next tile's gather (stays in flight through MFMA phases) --
    bool sflag = false;
    int ssidx = 0, six = 0, snseg = 0;
    if (t < 3) {
      int ew = sorted[row0 + (t + 1) * 64 + lane];
      if (wave == 0) {
        int ix = idx[ew];
        int prev = __shfl_up(ix, 1, 64);
        sflag = (lane == 0) || (ix != prev);
        unsigned long long mask = __ballot(sflag);
        snseg = (int)__popcll(mask);
        ssidx = (int)__popcll(mask & ((1ull << lane) - 1ull));
        six = ix;
      }
#pragma unroll
      for (int k = 0; k < 16; ++k) {
        int e = __shfl(ew, k * 4 + wave, 64);
        vbuf[k] = reinterpret_cast<const float4*>(X + (size_t)e * 256)[lane];
      }
      __builtin_amdgcn_sched_barrier(0);  // pin gather issue above the barrier
    }
    __syncthreads();   // buf[p] fully packed; seg[p] visible

    // seg writes for tile t+1 AFTER the barrier (prev reduce finished seg[1-p])
    if (t < 3 && wave == 0) {
      if (lane == 0) nsegS[1 - p] = snseg;
      if (sflag) {
        segLo[1 - p][ssidx] = lane;
        segN[1 - p][ssidx] = six;
      }
    }

    // ---- layer 1 ----
    f32x4 acc[4][4];
#pragma unroll
    for (int mi = 0; mi < 4; ++mi)
#pragma unroll
      for (int nj = 0; nj < 4; ++nj) acc[mi][nj] = (f32x4)0.0f;

#pragma unroll
    for (int s = 0; s < 8; ++s) {
      bf16x8 a[4], b[4];
#pragma unroll
      for (int mi = 0; mi < 4; ++mi)
        a[mi] = *reinterpret_cast<const bf16x8*>(&Xl[p][mi * 16 + m][s * 32 + q * 8]);
#pragma unroll
      for (int nj = 0; nj < 4; ++nj)
        b[nj] = *reinterpret_cast<const bf16x8*>(
            Wp1 + (size_t)(((wave * 4 + nj) * 8 + s) * 64 + lane) * 8);
      __builtin_amdgcn_s_setprio(1);
#pragma unroll
      for (int mi = 0; mi < 4; ++mi)
#pragma unroll
        for (int nj = 0; nj < 4; ++nj)
          acc[mi][nj] = __builtin_amdgcn_mfma_f32_16x16x32_bf16(a[mi], b[nj],
                                                                acc[mi][nj], 0, 0, 0);
      __builtin_amdgcn_s_setprio(0);
    }
    __syncthreads();   // done reading X(t)

#pragma unroll
    for (int mi = 0; mi < 4; ++mi)
#pragma unroll
      for (int nj = 0; nj < 4; ++nj)
#pragma unroll
        for (int r4 = 0; r4 < 4; ++r4) {
          float v = fmaxf(acc[mi][nj][r4] + bias1v[nj], 0.0f);
          Xl[p][mi * 16 + q * 4 + r4][wave * 64 + nj * 16 + m] = f2bf(v);
        }
    __syncthreads();   // Y1 ready

    // ---- layer 2 ----
#pragma unroll
    for (int mi = 0; mi < 4; ++mi)
#pragma unroll
      for (int nj = 0; nj < 4; ++nj) acc[mi][nj] = (f32x4)0.0f;

#pragma unroll
    for (int s = 0; s < 8; ++s) {
      bf16x8 a[4], b[4];
#pragma unroll
      for (int mi = 0; mi < 4; ++mi)
        a[mi] = *reinterpret_cast<const bf16x8*>(&Xl[p][mi * 16 + m][s * 32 + q * 8]);
#pragma unroll
      for (int nj = 0; nj < 4; ++nj)
        b[nj] = *reinterpret_cast<const bf16x8*>(
            Wp2 + (size_t)(((wave * 4 + nj) * 8 + s) * 64 + lane) * 8);
      __builtin_amdgcn_s_setprio(1);
#pragma unroll
      for (int mi = 0; mi < 4; ++mi)
#pragma unroll
        for (int nj = 0; nj < 4; ++nj)
          acc[mi][nj] = __builtin_amdgcn_mfma_f32_16x16x32_bf16(a[mi], b[nj],
                                                                acc[mi][nj], 0, 0, 0);
      __builtin_amdgcn_s_setprio(0);
    }

#pragma unroll
    for (int mi = 0; mi < 4; ++mi)
#pragma unroll
      for (int nj = 0; nj < 4; ++nj)
#pragma unroll
        for (int r4 = 0; r4 < 4; ++r4)
          acc[mi][nj][r4] = fmaxf(acc[mi][nj][r4] + bias2v[nj], 0.0f);

    // ---- in-register segmented reduce + scatter (tile t) ----
    int nseg = nsegS[p];
    for (int s = 0; s < nseg; ++s) {
      int lo = segLo[p][s];
      int hi = (s + 1 < nseg) ? segLo[p][s + 1] : 64;
      int node = segN[p][s];
      float sum[4] = {0.0f, 0.0f, 0.0f, 0.0f};
#pragma unroll
      for (int mi = 0; mi < 4; ++mi)
#pragma unroll
        for (int r4 = 0; r4 < 4; ++r4) {
          int row = mi * 16 + q * 4 + r4;
          float msk = (row >= lo && row < hi) ? 1.0f : 0.0f;
#pragma unroll
          for (int nj = 0; nj < 4; ++nj) sum[nj] = fmaf(msk, acc[mi][nj][r4], sum[nj]);
        }
      float scale = inv[node];
#pragma unroll
      for (int nj = 0; nj < 4; ++nj) {
        float v = sum[nj];
        v += __shfl_xor(v, 16, 64);
        v += __shfl_xor(v, 32, 64);
        if (q == 0 && v != 0.0f)
          atomicAdd(&out[(size_t)node * 256 + wave * 64 + nj * 16 + m], v * scale);
      }
    }

    // -- pack next tile into the other buffer (first vbuf use -> vmcnt here) --
    if (t < 3) {
#pragma unroll
      for (int k = 0; k < 16; ++k) {
        uint2 pk;
        pk.x = pack2bf(vbuf[k].x, vbuf[k].y);
        pk.y = pack2bf(vbuf[k].z, vbuf[k].w);
        *reinterpret_cast<uint2*>(&Xl[1 - p][k * 4 + wave][lane * 4]) = pk;
      }
    }
    // loop-top __syncthreads serves as the tile boundary barrier
  }
}

extern "C" void kernel_launch(void* const* d_in, const int* in_sizes, int n_in,
                              void* d_out, int out_size, void* d_ws, size_t ws_size,
                              hipStream_t stream) {
  const float* X   = (const float*)d_in[0];
  const int*   idx = (const int*)d_in[1];
  const float* W1  = (const float*)d_in[3];
  const float* b1  = (const float*)d_in[4];
  const float* W2  = (const float*)d_in[5];
  const float* b2  = (const float*)d_in[6];
  float* out = (float*)d_out;

  char* ws = (char*)d_ws;
  short* Wp     = (short*)(ws);                 // 262,144 B
  int*   cntA   = (int*)(ws + 262144);          // 1,280,000 B (counters; reused as sorted)
  int*   fillP  = (int*)(ws + 1542144);         // 1,280,000 B
  float* inv    = (float*)(ws + 2822144);       //    40,960 B
  int*   cursor = (int*)(ws + 2863104);         //         4 B
  int*   sorted = cntA;                         // alias: counters dead after alloc_k

  zero_repack_k<<<2048, 256, 0, stream>>>(W1, W2, Wp, cntA, cursor, out);
  hist_k<<<(NUM_E + 255) / 256, 256, 0, stream>>>(idx, cntA);
  alloc_k<<<40, 256, 0, stream>>>(cntA, fillP, inv, cursor);
  scatter_k<<<(NUM_E + 255) / 256, 256, 0, stream>>>(idx, fillP, sorted);
  fused_mlp_gather<<<NUM_E / 256, 256, 0, stream>>>(
      X, idx, sorted, Wp, Wp + 65536, b1, b2, inv, out);
}